// Round 15
// baseline (9120.872 us; speedup 1.0000x reference)
//
#include <hip/hip_runtime.h>
#include <hip/hip_fp16.h>
#include <math.h>

#define T_LEN 2048
#define NB 8
#define DD 512
#define HH 512
#define G4 2048   // 4*H
#define CAT2H 1024
#define JPAD 136  // 128 + 8 halfs: per-j-block padded stride (bank-conflict-free)

typedef _Float16 h2_t __attribute__((ext_vector_type(2)));

__device__ __forceinline__ h2_t f2h2(float x, float y) {
  h2_t r; r[0] = (_Float16)x; r[1] = (_Float16)y; return r;
}

// ---------- vector load helpers (fp32 or fp16 -> float4) ----------
__device__ __forceinline__ float4 ld4(const float* p) { return *(const float4*)p; }
__device__ __forceinline__ float4 ld4(const __half* p) {
  const __half2 a = *(const __half2*)p;
  const __half2 b = *(const __half2*)(p + 2);
  return make_float4(__half2float(a.x), __half2float(a.y),
                     __half2float(b.x), __half2float(b.y));
}
__device__ __forceinline__ void st4(float* p, float4 v) { *(float4*)p = v; }
__device__ __forceinline__ void st4(__half* p, float4 v) {
  *(__half2*)p = __floats2half2_rn(v.x, v.y);
  *(__half2*)(p + 2) = __floats2half2_rn(v.z, v.w);
}

// -------- tiled GEMM + bias, fdot2 inner loop (fp16 staged, fp32 accum) --------
// C = A(MxK) @ B(KxN) + bias. blockIdx.y selects (B0,bias0,C0)/(B1,bias1,C1).
template <typename TA, typename TC>
__global__ __launch_bounds__(256) void gemm_bias(
    const TA* __restrict__ A, const float* __restrict__ B0,
    const float* __restrict__ B1, const float* __restrict__ bias0,
    const float* __restrict__ bias1, TC* __restrict__ C0, TC* __restrict__ C1,
    int M, int N, int K) {
  const float* __restrict__ B = blockIdx.y ? B1 : B0;
  const float* __restrict__ bias = blockIdx.y ? bias1 : bias0;
  TC* __restrict__ C = blockIdx.y ? C1 : C0;
  __shared__ h2_t As2[8][132];
  __shared__ h2_t Bs2[8][132];
  const int nTiles = N >> 7;
  const int bx = blockIdx.x % nTiles;
  const int by = blockIdx.x / nTiles;
  const int tid = threadIdx.x;
  const int tx = tid & 15, ty = tid >> 4;
  const TA* Ab = A + (size_t)by * 128 * K;
  const float* Bb = B + ((size_t)bx << 7);
  float acc[8][8];
#pragma unroll
  for (int i = 0; i < 8; i++)
#pragma unroll
    for (int j = 0; j < 8; j++) acc[i][j] = 0.f;

  for (int k0 = 0; k0 < K; k0 += 16) {
    __syncthreads();
#pragma unroll
    for (int i = 0; i < 2; i++) {
      int idx = i * 256 + tid;
      int m = idx >> 2, kv = idx & 3;
      float4 va = ld4(Ab + (size_t)m * K + k0 + kv * 4);
      As2[kv * 2][m] = f2h2(va.x, va.y);
      As2[kv * 2 + 1][m] = f2h2(va.z, va.w);
    }
#pragma unroll
    for (int i = 0; i < 2; i++) {
      int idx = i * 256 + tid;
      int kp = idx >> 6, n0 = (idx & 63) * 2;
      const float* bp0 = Bb + (size_t)(k0 + 2 * kp) * N + n0;
      float2 r0 = *(const float2*)bp0;
      float2 r1 = *(const float2*)(bp0 + N);
      Bs2[kp][n0] = f2h2(r0.x, r1.x);
      Bs2[kp][n0 + 1] = f2h2(r0.y, r1.y);
    }
    __syncthreads();
#pragma unroll
    for (int kp = 0; kp < 8; kp++) {
      h2_t a2[8], b2[8];
      *(float4*)&a2[0] = *(const float4*)&As2[kp][ty * 8];
      *(float4*)&a2[4] = *(const float4*)&As2[kp][ty * 8 + 4];
      *(float4*)&b2[0] = *(const float4*)&Bs2[kp][tx * 8];
      *(float4*)&b2[4] = *(const float4*)&Bs2[kp][tx * 8 + 4];
#pragma unroll
      for (int i = 0; i < 8; i++)
#pragma unroll
        for (int j = 0; j < 8; j++)
          acc[i][j] = __builtin_amdgcn_fdot2(a2[i], b2[j], acc[i][j], false);
    }
  }
  const int row0 = by * 128 + ty * 8;
  const int col0 = bx * 128 + tx * 8;
  float bv[8];
  *(float4*)&bv[0] = *(const float4*)&bias[col0];
  *(float4*)&bv[4] = *(const float4*)&bias[col0 + 4];
#pragma unroll
  for (int i = 0; i < 8; i++) {
    float4 o0 = make_float4(acc[i][0] + bv[0], acc[i][1] + bv[1],
                            acc[i][2] + bv[2], acc[i][3] + bv[3]);
    float4 o1 = make_float4(acc[i][4] + bv[4], acc[i][5] + bv[5],
                            acc[i][6] + bv[6], acc[i][7] + bv[7]);
    st4(&C[(size_t)(row0 + i) * N + col0], o0);
    st4(&C[(size_t)(row0 + i) * N + col0 + 4], o1);
  }
}

// ---------------- persistent bidirectional LSTM scan (one layer) ----------------
// R14 body (proven 3.62ms) + R15 delta: phase-offset DUAL pollers per unit.
// Thread t polls units t and (t+256)&511 (distinct addresses -> no MSHR merge);
// the two pollers of any unit are in opposite phase groups, group B (t>=256)
// primes after s_sleep(6) (~384cy ~ L/2) -> per-unit sampling period halves.
// Discoverer writes h16 + a 32-bit LDS tag (=want, unique per step/launch);
// threads exit when both their units are tagged (cheap LDS spin). Mailbox
// protocol (R5, 5x proven), fdot2 compute, single barrier/step: unchanged.
__device__ __forceinline__ float sigmf_(float x) {
  return 1.f / (1.f + __expf(-x));
}
__device__ __forceinline__ float tanhf_(float x) {
  return 1.f - 2.f / (1.f + __expf(2.f * x));
}
__device__ __forceinline__ unsigned long long agld_(const unsigned long long* p) {
  return __hip_atomic_load(p, __ATOMIC_RELAXED, __HIP_MEMORY_SCOPE_AGENT);
}

__global__ __launch_bounds__(512, 2) void lstm_scan(
    const __half* __restrict__ Pf, const __half* __restrict__ Pb,
    const float* __restrict__ Whf, const float* __restrict__ Whb,
    const int* __restrict__ seqlen, __half* __restrict__ cat,
    unsigned long long* hbuf, float* diag, int tagbase) {
  const int w = blockIdx.x;
  const int chain = w & 15;
  const int us = w >> 4;
  const int dir = chain & 1;
  const int b = chain >> 1;
  const int t = threadIdx.x;
  const int lane = t & 63;
  const int u = t >> 4;         // 0..31: unit within slice (compute mapping)
  const int g = (t >> 2) & 3;   // gate
  const int j = t & 3;          // k-quarter
  const int C = g * HH + us * 32 + u;
  const int isPub = (t & 15) == 0;

  const float* __restrict__ Wh = dir ? Whb : Whf;
  const __half* __restrict__ P = dir ? Pb : Pf;
  const int L = seqlen[b];

  __shared__ __half h16[2][4 * JPAD];  // [parity][j-block padded]
  __shared__ unsigned hword[2][HH];    // [parity][unit]: discovery tag (=want)

  h2_t wr2[64];
  {
    const float* wp = Wh + (size_t)(j * 128) * G4 + C;
#pragma unroll
    for (int m = 0; m < 64; m++)
      wr2[m] = f2h2(wp[(size_t)(2 * m) * G4], wp[(size_t)(2 * m + 1) * G4]);
  }
  float c_state = 0.f;

  // hbuf: [slot(2)][ci(16)][unit(512)] u64 (tag<<32 | f32 h bits)
  unsigned long long* hb_base = hbuf + ((size_t)dir * NB + b) * HH;
  const size_t slotStride = (size_t)2 * NB * HH;
  const unsigned tb = (unsigned)tagbase;

  hword[0][t] = 0;  // 0 never equals want (want >= 1)
  hword[1][t] = 0;
  if (isPub) {  // init slot 0: h(-1)=0 tagged tb for own unit
    __hip_atomic_store(hb_base + us * 32 + u, ((unsigned long long)tb << 32),
                       __ATOMIC_RELAXED, __HIP_MEMORY_SCOPE_AGENT);
  }
  __syncthreads();

  for (int s = 0; s < T_LEN; s++) {
    const int tin = dir ? ((s < L) ? (L - 1 - s) : s) : s;
    float p0 = 0.f, p1 = 0.f, p2 = 0.f, p3 = 0.f;
    if (isPub) {  // P prefetch for this unit's 4 gates; hides under the spin
      const __half* pr = P + ((size_t)b * T_LEN + tin) * G4 + us * 32 + u;
      p0 = __half2float(pr[0]);
      p1 = __half2float(pr[HH]);
      p2 = __half2float(pr[2 * HH]);
      p3 = __half2float(pr[3 * HH]);
    }

    // dual-poller spin (see header comment)
    int dead = 0;
    {
      const unsigned want = tb + (unsigned)s;
      const int par = s & 1;
      unsigned long long* sbase = hb_base + (size_t)par * slotStride;
      const int u1 = (t + 256) & 511;
      unsigned long long* A0 = sbase + t;
      unsigned long long* A1 = sbase + u1;
      unsigned* hw = &hword[par][0];
      if (t >= 256) __builtin_amdgcn_s_sleep(6);  // ~384cy phase offset
      unsigned long long g0 = agld_(A0);
      unsigned long long g1 = agld_(A1);
      int done0 = 0, done1 = 0, tries = 0;
      for (;;) {
        if (!done0) {
          if ((unsigned)(g0 >> 32) == want) {
            h16[par][(t >> 7) * JPAD + (t & 127)] =
                __float2half(__uint_as_float((unsigned)g0));
            __hip_atomic_store(&hw[t], want, __ATOMIC_RELAXED,
                               __HIP_MEMORY_SCOPE_WORKGROUP);
            done0 = 1;
          } else if (__hip_atomic_load(&hw[t], __ATOMIC_RELAXED,
                                       __HIP_MEMORY_SCOPE_WORKGROUP) == want) {
            done0 = 1;
          } else {
            g0 = agld_(A0);
          }
        }
        if (!done1) {
          if ((unsigned)(g1 >> 32) == want) {
            h16[par][(u1 >> 7) * JPAD + (u1 & 127)] =
                __float2half(__uint_as_float((unsigned)g1));
            __hip_atomic_store(&hw[u1], want, __ATOMIC_RELAXED,
                               __HIP_MEMORY_SCOPE_WORKGROUP);
            done1 = 1;
          } else if (__hip_atomic_load(&hw[u1], __ATOMIC_RELAXED,
                                       __HIP_MEMORY_SCOPE_WORKGROUP) == want) {
            done1 = 1;
          } else {
            g1 = agld_(A1);
          }
        }
        if (done0 & done1) break;
        if (++tries > (1 << 20)) { dead = 1; break; }
      }
    }
    if (__syncthreads_or(dead)) {  // the ONLY barrier per step
      if (t == 0) { atomicAdd(diag + 1, 1.0f); diag[2] = (float)s; }
      break;
    }

    float a = 0.f;
    {
      const __half* hk = &h16[s & 1][j * JPAD];
#pragma unroll
      for (int i = 0; i < 16; i++) {
        float4 hv4 = *(const float4*)&hk[i * 8];  // bcast within 16-lane group
        const h2_t* hp2 = (const h2_t*)&hv4;
        a = __builtin_amdgcn_fdot2(hp2[0], wr2[i * 4 + 0], a, false);
        a = __builtin_amdgcn_fdot2(hp2[1], wr2[i * 4 + 1], a, false);
        a = __builtin_amdgcn_fdot2(hp2[2], wr2[i * 4 + 2], a, false);
        a = __builtin_amdgcn_fdot2(hp2[3], wr2[i * 4 + 3], a, false);
      }
    }
    // k-reduce within quad (j dimension)
    a += __shfl_xor(a, 1, 64);
    a += __shfl_xor(a, 2, 64);
    // gate gather within the 16-lane unit group
    const int base = lane & ~15;
    float d0 = __shfl(a, base + 0, 64);
    float d1 = __shfl(a, base + 4, 64);
    float d2 = __shfl(a, base + 8, 64);
    float d3 = __shfl(a, base + 12, 64);

    if (isPub) {
      float g0 = p0 + d0, g1 = p1 + d1, g2 = p2 + d2, g3 = p3 + d3;
      c_state = sigmf_(g1) * c_state + sigmf_(g0) * tanhf_(g2);
      float hn = sigmf_(g3) * tanhf_(c_state);
      unsigned long long pv =
          ((unsigned long long)(tb + (unsigned)s + 1u) << 32) |
          (unsigned long long)__float_as_uint(hn);
      __hip_atomic_store(
          hb_base + (size_t)((s + 1) & 1) * slotStride + us * 32 + u, pv,
          __ATOMIC_RELAXED, __HIP_MEMORY_SCOPE_AGENT);
      cat[((size_t)b * T_LEN + tin) * CAT2H + dir * HH + us * 32 + u] =
          __float2half(hn);
    }
    // no trailing barrier: h16/hword are parity double-buffered; writing
    // parity p again requires passing the next barrier, which every reader
    // of parity p also passed. Same proof as R14.
  }
}

// Failure-signature marker: writes a decodable code into out[0] ONLY on failure.
__global__ void diag_mark(const float* diag, float* out, float code_ws, int wsfail) {
  if (wsfail) { out[0] = code_ws; return; }
  float nd = diag[1];
  if (nd > 0.f) out[0] = 1.0e7f + nd * 1.0e4f + diag[2];
}

extern "C" void kernel_launch(void* const* d_in, const int* in_sizes, int n_in,
                              void* d_out, int out_size, void* d_ws, size_t ws_size,
                              hipStream_t stream) {
  const float* inputs = (const float*)d_in[0];
  const int* seqlen = (const int*)d_in[1];
  const float* Wx_f = (const float*)d_in[2];
  const float* Wh_f = (const float*)d_in[3];
  const float* b_f  = (const float*)d_in[4];
  const float* Wx_b = (const float*)d_in[5];
  const float* Wh_b = (const float*)d_in[6];
  const float* b_b  = (const float*)d_in[7];
  const float* Wp   = (const float*)d_in[8];
  const float* bp   = (const float*)d_in[9];
  float* out = (float*)d_out;

  // ws: diag(256B) | hbuf u64 @256 (128KiB) | Pf | Pb | cat | x1 (fp16)
  const size_t oHB = 256;
  const size_t szHB = (size_t)2 * 16 * HH * sizeof(unsigned long long);  // 131072
  const size_t oPf = oHB + szHB;
  const size_t oPb = oPf + 67108864ull;
  const size_t oCat = oPb + 67108864ull;
  const size_t oX1 = oCat + 33554432ull;
  const size_t need = oX1 + 16777216ull;

  if (ws_size < need) {
    hipMemsetAsync(d_out, 0, (size_t)out_size * sizeof(float), stream);
    float code = 1.0e8f + (float)(ws_size / (1024.0 * 1024.0)) * 10.0f;
    diag_mark<<<1, 1, 0, stream>>>(nullptr, out, code, 1);
    return;
  }
  char* ws = (char*)d_ws;
  float* diag = (float*)ws;
  unsigned long long* hbuf = (unsigned long long*)(ws + oHB);
  __half* Pf = (__half*)(ws + oPf);
  __half* Pb = (__half*)(ws + oPb);
  __half* cat = (__half*)(ws + oCat);
  __half* x1 = (__half*)(ws + oX1);

  hipMemsetAsync(diag, 0, 256, stream);

  const int MM = NB * T_LEN;  // 16384

  // ---- layer 0: both input projections in ONE dispatch (blockIdx.y) ----
  gemm_bias<float, __half>
      <<<dim3((MM / 128) * (G4 / 128), 2), dim3(256), 0, stream>>>(
          inputs, Wx_f, Wx_b, b_f, b_b, Pf, Pb, MM, G4, DD);
  lstm_scan<<<dim3(256), dim3(512), 0, stream>>>(Pf, Pb, Wh_f, Wh_b, seqlen, cat,
                                                 hbuf, diag, 1);
  gemm_bias<__half, __half>
      <<<dim3((MM / 128) * (DD / 128), 1), dim3(256), 0, stream>>>(
          cat, Wp, Wp, bp, bp, x1, x1, MM, DD, CAT2H);

  // ---- layer 1 ----
  gemm_bias<__half, __half>
      <<<dim3((MM / 128) * (G4 / 128), 2), dim3(256), 0, stream>>>(
          x1, Wx_f + (size_t)DD * G4, Wx_b + (size_t)DD * G4, b_f + G4, b_b + G4,
          Pf, Pb, MM, G4, DD);
  lstm_scan<<<dim3(256), dim3(512), 0, stream>>>(
      Pf, Pb, Wh_f + (size_t)HH * G4, Wh_b + (size_t)HH * G4, seqlen, cat, hbuf,
      diag, 3000);
  gemm_bias<__half, float>
      <<<dim3((MM / 128) * (DD / 128), 1), dim3(256), 0, stream>>>(
          cat, Wp + (size_t)CAT2H * DD, Wp + (size_t)CAT2H * DD, bp + DD,
          bp + DD, out, out, MM, DD, CAT2H);

  diag_mark<<<1, 1, 0, stream>>>(diag, out, 0.f, 0);
}

// Round 16
// 8063.404 us; speedup vs baseline: 1.1311x; 1.1311x over previous
//
#include <hip/hip_runtime.h>
#include <hip/hip_fp16.h>
#include <math.h>

#define T_LEN 2048
#define NB 8
#define DD 512
#define HH 512
#define G4 2048   // 4*H
#define CAT2H 1024
#define JPAD 136  // 128 + 8 halfs: per-j-block padded stride (bank-conflict-free)

typedef _Float16 h2_t __attribute__((ext_vector_type(2)));

__device__ __forceinline__ h2_t f2h2(float x, float y) {
  h2_t r; r[0] = (_Float16)x; r[1] = (_Float16)y; return r;
}

// ---------- vector load helpers (fp32 or fp16 -> float4) ----------
__device__ __forceinline__ float4 ld4(const float* p) { return *(const float4*)p; }
__device__ __forceinline__ float4 ld4(const __half* p) {
  const __half2 a = *(const __half2*)p;
  const __half2 b = *(const __half2*)(p + 2);
  return make_float4(__half2float(a.x), __half2float(a.y),
                     __half2float(b.x), __half2float(b.y));
}
__device__ __forceinline__ void st4(float* p, float4 v) { *(float4*)p = v; }
__device__ __forceinline__ void st4(__half* p, float4 v) {
  *(__half2*)p = __floats2half2_rn(v.x, v.y);
  *(__half2*)(p + 2) = __floats2half2_rn(v.z, v.w);
}

// -------- tiled GEMM + bias, fdot2 inner loop (fp16 staged, fp32 accum) --------
// C = A(MxK) @ B(KxN) + bias. blockIdx.y selects (B0,bias0,C0)/(B1,bias1,C1).
template <typename TA, typename TC>
__global__ __launch_bounds__(256) void gemm_bias(
    const TA* __restrict__ A, const float* __restrict__ B0,
    const float* __restrict__ B1, const float* __restrict__ bias0,
    const float* __restrict__ bias1, TC* __restrict__ C0, TC* __restrict__ C1,
    int M, int N, int K) {
  const float* __restrict__ B = blockIdx.y ? B1 : B0;
  const float* __restrict__ bias = blockIdx.y ? bias1 : bias0;
  TC* __restrict__ C = blockIdx.y ? C1 : C0;
  __shared__ h2_t As2[8][132];
  __shared__ h2_t Bs2[8][132];
  const int nTiles = N >> 7;
  const int bx = blockIdx.x % nTiles;
  const int by = blockIdx.x / nTiles;
  const int tid = threadIdx.x;
  const int tx = tid & 15, ty = tid >> 4;
  const TA* Ab = A + (size_t)by * 128 * K;
  const float* Bb = B + ((size_t)bx << 7);
  float acc[8][8];
#pragma unroll
  for (int i = 0; i < 8; i++)
#pragma unroll
    for (int j = 0; j < 8; j++) acc[i][j] = 0.f;

  for (int k0 = 0; k0 < K; k0 += 16) {
    __syncthreads();
#pragma unroll
    for (int i = 0; i < 2; i++) {
      int idx = i * 256 + tid;
      int m = idx >> 2, kv = idx & 3;
      float4 va = ld4(Ab + (size_t)m * K + k0 + kv * 4);
      As2[kv * 2][m] = f2h2(va.x, va.y);
      As2[kv * 2 + 1][m] = f2h2(va.z, va.w);
    }
#pragma unroll
    for (int i = 0; i < 2; i++) {
      int idx = i * 256 + tid;
      int kp = idx >> 6, n0 = (idx & 63) * 2;
      const float* bp0 = Bb + (size_t)(k0 + 2 * kp) * N + n0;
      float2 r0 = *(const float2*)bp0;
      float2 r1 = *(const float2*)(bp0 + N);
      Bs2[kp][n0] = f2h2(r0.x, r1.x);
      Bs2[kp][n0 + 1] = f2h2(r0.y, r1.y);
    }
    __syncthreads();
#pragma unroll
    for (int kp = 0; kp < 8; kp++) {
      h2_t a2[8], b2[8];
      *(float4*)&a2[0] = *(const float4*)&As2[kp][ty * 8];
      *(float4*)&a2[4] = *(const float4*)&As2[kp][ty * 8 + 4];
      *(float4*)&b2[0] = *(const float4*)&Bs2[kp][tx * 8];
      *(float4*)&b2[4] = *(const float4*)&Bs2[kp][tx * 8 + 4];
#pragma unroll
      for (int i = 0; i < 8; i++)
#pragma unroll
        for (int j = 0; j < 8; j++)
          acc[i][j] = __builtin_amdgcn_fdot2(a2[i], b2[j], acc[i][j], false);
    }
  }
  const int row0 = by * 128 + ty * 8;
  const int col0 = bx * 128 + tx * 8;
  float bv[8];
  *(float4*)&bv[0] = *(const float4*)&bias[col0];
  *(float4*)&bv[4] = *(const float4*)&bias[col0 + 4];
#pragma unroll
  for (int i = 0; i < 8; i++) {
    float4 o0 = make_float4(acc[i][0] + bv[0], acc[i][1] + bv[1],
                            acc[i][2] + bv[2], acc[i][3] + bv[3]);
    float4 o1 = make_float4(acc[i][4] + bv[4], acc[i][5] + bv[5],
                            acc[i][6] + bv[6], acc[i][7] + bv[7]);
    st4(&C[(size_t)(row0 + i) * N + col0], o0);
    st4(&C[(size_t)(row0 + i) * N + col0 + 4], o1);
  }
}

// ---------------- persistent bidirectional LSTM scan (one layer) ----------------
// R5 geometry + mailbox protocol VERBATIM (4x proven): 256 WGs x 512 thr;
// chain=(dir,b) -> 16 WGs; WG owns 32 units; u64 (tag|f32 h) relaxed AGENT
// atomics via LLC (sc0/intra-XCD ruled out: R4+R13 show sc0 loads run at LLC
// latency, non-sc0 are stale; replication/summary/exchange/dual-poll all
// regressed: R6/R8/R9/R15), double-buffered by step parity, unique tags.
// R14 = R12's single-barrier layout + bank-conflict fix: thread t = u*16+g*4+j
// computes column (g,u) over k-quarter j; k-reduce = 2 shfl_xor in the quad;
// gate gather = 3 shfl in the 16-lane group; cell+publish in lane (t&15)==0.
// h16 j-blocks padded to 136 halfs (272B = 68 words, 68%32=4) so the 4
// j-groups' broadcast reads hit disjoint bank sets (R12's 8e8 conflicts -> 0).
__device__ __forceinline__ float sigmf_(float x) {
  return 1.f / (1.f + __expf(-x));
}
__device__ __forceinline__ float tanhf_(float x) {
  return 1.f - 2.f / (1.f + __expf(2.f * x));
}

__global__ __launch_bounds__(512, 2) void lstm_scan(
    const __half* __restrict__ Pf, const __half* __restrict__ Pb,
    const float* __restrict__ Whf, const float* __restrict__ Whb,
    const int* __restrict__ seqlen, __half* __restrict__ cat,
    unsigned long long* hbuf, float* diag, int tagbase) {
  const int w = blockIdx.x;
  const int chain = w & 15;
  const int us = w >> 4;
  const int dir = chain & 1;
  const int b = chain >> 1;
  const int t = threadIdx.x;
  const int lane = t & 63;
  const int u = t >> 4;         // 0..31: unit within slice
  const int g = (t >> 2) & 3;   // gate
  const int j = t & 3;          // k-quarter
  const int C = g * HH + us * 32 + u;
  const int isPub = (t & 15) == 0;

  const float* __restrict__ Wh = dir ? Whb : Whf;
  const __half* __restrict__ P = dir ? Pb : Pf;
  const int L = seqlen[b];

  __shared__ __half h16[2][4 * JPAD];  // [parity][j-block padded]

  h2_t wr2[64];
  {
    const float* wp = Wh + (size_t)(j * 128) * G4 + C;
#pragma unroll
    for (int m = 0; m < 64; m++)
      wr2[m] = f2h2(wp[(size_t)(2 * m) * G4], wp[(size_t)(2 * m + 1) * G4]);
  }
  float c_state = 0.f;

  // hbuf: [slot(2)][ci(16)][unit(512)] u64 (tag<<32 | f32 h bits)
  unsigned long long* hb_base = hbuf + ((size_t)dir * NB + b) * HH;
  const size_t slotStride = (size_t)2 * NB * HH;
  const unsigned tb = (unsigned)tagbase;

  if (isPub) {  // init slot 0: h(-1)=0 tagged tb for own unit
    __hip_atomic_store(hb_base + us * 32 + u, ((unsigned long long)tb << 32),
                       __ATOMIC_RELAXED, __HIP_MEMORY_SCOPE_AGENT);
  }

  for (int s = 0; s < T_LEN; s++) {
    const int tin = dir ? ((s < L) ? (L - 1 - s) : s) : s;
    float p0 = 0.f, p1 = 0.f, p2 = 0.f, p3 = 0.f;
    if (isPub) {  // P prefetch for this unit's 4 gates; hides under the spin
      const __half* pr = P + ((size_t)b * T_LEN + tin) * G4 + us * 32 + u;
      p0 = __half2float(pr[0]);
      p1 = __half2float(pr[HH]);
      p2 = __half2float(pr[2 * HH]);
      p3 = __half2float(pr[3 * HH]);
    }

    // spin: mailbox unit t must carry tag == tb+s (R5 protocol, unchanged)
    int dead = 0;
    {
      const unsigned want = tb + (unsigned)s;
      unsigned long long* hp = hb_base + (size_t)(s & 1) * slotStride + t;
      unsigned long long v;
      int tries = 0;
      for (;;) {
        v = __hip_atomic_load(hp, __ATOMIC_RELAXED, __HIP_MEMORY_SCOPE_AGENT);
        if ((unsigned)(v >> 32) == want) break;
        if (++tries > (1 << 20)) { dead = 1; break; }
      }
      h16[s & 1][(t >> 7) * JPAD + (t & 127)] =
          __float2half(__uint_as_float((unsigned)v));
    }
    if (__syncthreads_or(dead)) {  // the ONLY barrier per step
      if (t == 0) { atomicAdd(diag + 1, 1.0f); diag[2] = (float)s; }
      break;
    }

    float a = 0.f;
    {
      const __half* hk = &h16[s & 1][j * JPAD];
#pragma unroll
      for (int i = 0; i < 16; i++) {
        float4 hv4 = *(const float4*)&hk[i * 8];  // bcast within 16-lane group
        const h2_t* hp2 = (const h2_t*)&hv4;
        a = __builtin_amdgcn_fdot2(hp2[0], wr2[i * 4 + 0], a, false);
        a = __builtin_amdgcn_fdot2(hp2[1], wr2[i * 4 + 1], a, false);
        a = __builtin_amdgcn_fdot2(hp2[2], wr2[i * 4 + 2], a, false);
        a = __builtin_amdgcn_fdot2(hp2[3], wr2[i * 4 + 3], a, false);
      }
    }
    // k-reduce within quad (j dimension)
    a += __shfl_xor(a, 1, 64);
    a += __shfl_xor(a, 2, 64);
    // gate gather within the 16-lane unit group
    const int base = lane & ~15;
    float d0 = __shfl(a, base + 0, 64);
    float d1 = __shfl(a, base + 4, 64);
    float d2 = __shfl(a, base + 8, 64);
    float d3 = __shfl(a, base + 12, 64);

    if (isPub) {
      float g0 = p0 + d0, g1 = p1 + d1, g2 = p2 + d2, g3 = p3 + d3;
      c_state = sigmf_(g1) * c_state + sigmf_(g0) * tanhf_(g2);
      float hn = sigmf_(g3) * tanhf_(c_state);
      unsigned long long pv =
          ((unsigned long long)(tb + (unsigned)s + 1u) << 32) |
          (unsigned long long)__float_as_uint(hn);
      __hip_atomic_store(
          hb_base + (size_t)((s + 1) & 1) * slotStride + us * 32 + u, pv,
          __ATOMIC_RELAXED, __HIP_MEMORY_SCOPE_AGENT);
      cat[((size_t)b * T_LEN + tin) * CAT2H + dir * HH + us * 32 + u] =
          __float2half(hn);
    }
    // no trailing barrier: h16 is parity double-buffered; writing h16[s&1]
    // again requires passing barrier(s+1), which every step-s reader passed.
  }
}

// Failure-signature marker: writes a decodable code into out[0] ONLY on failure.
__global__ void diag_mark(const float* diag, float* out, float code_ws, int wsfail) {
  if (wsfail) { out[0] = code_ws; return; }
  float nd = diag[1];
  if (nd > 0.f) out[0] = 1.0e7f + nd * 1.0e4f + diag[2];
}

extern "C" void kernel_launch(void* const* d_in, const int* in_sizes, int n_in,
                              void* d_out, int out_size, void* d_ws, size_t ws_size,
                              hipStream_t stream) {
  const float* inputs = (const float*)d_in[0];
  const int* seqlen = (const int*)d_in[1];
  const float* Wx_f = (const float*)d_in[2];
  const float* Wh_f = (const float*)d_in[3];
  const float* b_f  = (const float*)d_in[4];
  const float* Wx_b = (const float*)d_in[5];
  const float* Wh_b = (const float*)d_in[6];
  const float* b_b  = (const float*)d_in[7];
  const float* Wp   = (const float*)d_in[8];
  const float* bp   = (const float*)d_in[9];
  float* out = (float*)d_out;

  // ws: diag(256B) | hbuf u64 @256 (128KiB) | Pf | Pb | cat | x1 (fp16)
  const size_t oHB = 256;
  const size_t szHB = (size_t)2 * 16 * HH * sizeof(unsigned long long);  // 131072
  const size_t oPf = oHB + szHB;
  const size_t oPb = oPf + 67108864ull;
  const size_t oCat = oPb + 67108864ull;
  const size_t oX1 = oCat + 33554432ull;
  const size_t need = oX1 + 16777216ull;

  if (ws_size < need) {
    hipMemsetAsync(d_out, 0, (size_t)out_size * sizeof(float), stream);
    float code = 1.0e8f + (float)(ws_size / (1024.0 * 1024.0)) * 10.0f;
    diag_mark<<<1, 1, 0, stream>>>(nullptr, out, code, 1);
    return;
  }
  char* ws = (char*)d_ws;
  float* diag = (float*)ws;
  unsigned long long* hbuf = (unsigned long long*)(ws + oHB);
  __half* Pf = (__half*)(ws + oPf);
  __half* Pb = (__half*)(ws + oPb);
  __half* cat = (__half*)(ws + oCat);
  __half* x1 = (__half*)(ws + oX1);

  hipMemsetAsync(diag, 0, 256, stream);

  const int MM = NB * T_LEN;  // 16384

  // ---- layer 0: both input projections in ONE dispatch (blockIdx.y) ----
  gemm_bias<float, __half>
      <<<dim3((MM / 128) * (G4 / 128), 2), dim3(256), 0, stream>>>(
          inputs, Wx_f, Wx_b, b_f, b_b, Pf, Pb, MM, G4, DD);
  lstm_scan<<<dim3(256), dim3(512), 0, stream>>>(Pf, Pb, Wh_f, Wh_b, seqlen, cat,
                                                 hbuf, diag, 1);
  gemm_bias<__half, __half>
      <<<dim3((MM / 128) * (DD / 128), 1), dim3(256), 0, stream>>>(
          cat, Wp, Wp, bp, bp, x1, x1, MM, DD, CAT2H);

  // ---- layer 1 ----
  gemm_bias<__half, __half>
      <<<dim3((MM / 128) * (G4 / 128), 2), dim3(256), 0, stream>>>(
          x1, Wx_f + (size_t)DD * G4, Wx_b + (size_t)DD * G4, b_f + G4, b_b + G4,
          Pf, Pb, MM, G4, DD);
  lstm_scan<<<dim3(256), dim3(512), 0, stream>>>(
      Pf, Pb, Wh_f + (size_t)HH * G4, Wh_b + (size_t)HH * G4, seqlen, cat, hbuf,
      diag, 3000);
  gemm_bias<__half, float>
      <<<dim3((MM / 128) * (DD / 128), 1), dim3(256), 0, stream>>>(
          cat, Wp + (size_t)CAT2H * DD, Wp + (size_t)CAT2H * DD, bp + DD,
          bp + DD, out, out, MM, DD, CAT2H);

  diag_mark<<<1, 1, 0, stream>>>(diag, out, 0.f, 0);
}